// Round 1
// baseline (1194.557 us; speedup 1.0000x reference)
//
#include <hip/hip_runtime.h>

#define NN 50000
#define NE 800000

typedef __bf16 bf16_t;
typedef __bf16 bf16x8 __attribute__((ext_vector_type(8)));
typedef float f32x4 __attribute__((ext_vector_type(4)));

// ---- workspace layout (bytes) ----
#define SUM_B (NN * 128 * 4)
#define CNT_B (NN * 4)
#define SUM_OFF 0
#define CNT_OFF (SUM_OFF + SUM_B)
#define W1A_OFF (CNT_OFF + CNT_B)
#define W1A_B (256 * 256 * 2)
#define W1B_OFF (W1A_OFF + W1A_B)
#define W1B_B (128 * 256 * 2)
#define W2A_OFF (W1B_OFF + W1B_B)
#define W2A_B (256 * 384 * 2)
#define W2B_OFF (W2A_OFF + W2A_B)
#define W2B_B (128 * 256 * 2)

// Convert W[k][n] (row-major [K][Nn] fp32) -> Wt[n][k] bf16 (k contiguous),
// so a B-fragment (n = lane&15, k = quad*8+j) is one 16-byte load per lane.
__global__ __launch_bounds__(256) void transpose_bf16(
    const float* __restrict__ src, bf16_t* __restrict__ dst, int K, int Nn) {
  int idx = blockIdx.x * 256 + threadIdx.x;
  if (idx >= K * Nn) return;
  int n = idx / K;
  int k = idx - n * K;
  dst[idx] = (bf16_t)src[k * Nn + n];
}

// Edge MLP: h = relu([x[row]|ea] @ W1a + b1a) @ W1b + b1b ; scatter-add to sum[col]
__global__ __launch_bounds__(256) void edge_mlp(
    const float* __restrict__ x, const int* __restrict__ ei,
    const float* __restrict__ ea,
    const bf16_t* __restrict__ Wt1a, const float* __restrict__ b1a,
    const bf16_t* __restrict__ Wt1b, const float* __restrict__ b1b,
    float* __restrict__ sum, float* __restrict__ cnt) {
  __shared__ __align__(16) bf16_t As[64][264];  // A tile, reused as hidden tile
  __shared__ int rowS[64];
  __shared__ int colS[64];
  const int tid = threadIdx.x;
  const int lane = tid & 63;
  const int wave = tid >> 6;
  const int e0 = blockIdx.x * 64;

  if (tid < 64) {
    rowS[tid] = ei[e0 + tid];
    int c = ei[NE + e0 + tid];
    colS[tid] = c;
    atomicAdd(&cnt[c], 1.0f);  // one count per edge, exactly once
  }
  __syncthreads();

  // ---- stage A = [x[row] | edge_attr] as bf16: 64 rows x 256 cols ----
  {
    const int t_in = tid & 63;   // 64 threads cover one row (256 floats as float4)
    const int esub = tid >> 6;
    const int c0 = t_in * 4;
#pragma unroll
    for (int it = 0; it < 16; ++it) {
      const int i = it * 4 + esub;
      float4 f;
      if (c0 < 128) {
        f = *(const float4*)(x + rowS[i] * 128 + c0);
      } else {
        f = *(const float4*)(ea + (e0 + i) * 128 + (c0 - 128));
      }
      union { bf16_t h[4]; uint2 u; } pk;
      pk.h[0] = (bf16_t)f.x; pk.h[1] = (bf16_t)f.y;
      pk.h[2] = (bf16_t)f.z; pk.h[3] = (bf16_t)f.w;
      *(uint2*)&As[i][c0] = pk.u;
    }
  }
  __syncthreads();

  const int lr = lane & 15;
  const int lq = lane >> 4;

  // ---- layer 1: hidden(64x256) = relu(A @ W1a + b1a); wave owns 64 cols ----
  const int n_off = wave * 64;
  float bias1[4];
#pragma unroll
  for (int nt = 0; nt < 4; ++nt) bias1[nt] = b1a[n_off + nt * 16 + lr];

  f32x4 acc[4][4];
#pragma unroll
  for (int mt = 0; mt < 4; ++mt)
#pragma unroll
    for (int nt = 0; nt < 4; ++nt) acc[mt][nt] = (f32x4){0.f, 0.f, 0.f, 0.f};

#pragma unroll
  for (int ks = 0; ks < 8; ++ks) {
    const int k0 = ks * 32 + lq * 8;
    bf16x8 af[4], bv[4];
#pragma unroll
    for (int mt = 0; mt < 4; ++mt)
      af[mt] = *(const bf16x8*)&As[mt * 16 + lr][k0];
#pragma unroll
    for (int nt = 0; nt < 4; ++nt)
      bv[nt] = *(const bf16x8*)&Wt1a[(n_off + nt * 16 + lr) * 256 + k0];
#pragma unroll
    for (int mt = 0; mt < 4; ++mt)
#pragma unroll
      for (int nt = 0; nt < 4; ++nt)
        acc[mt][nt] = __builtin_amdgcn_mfma_f32_16x16x32_bf16(
            af[mt], bv[nt], acc[mt][nt], 0, 0, 0);
  }
  __syncthreads();  // everyone done reading As before overwrite
#pragma unroll
  for (int mt = 0; mt < 4; ++mt)
#pragma unroll
    for (int nt = 0; nt < 4; ++nt) {
      const int row = mt * 16 + lq * 4;
      const int colF = n_off + nt * 16 + lr;
#pragma unroll
      for (int r = 0; r < 4; ++r) {
        float v = acc[mt][nt][r] + bias1[nt];
        As[row + r][colF] = (bf16_t)fmaxf(v, 0.f);
      }
    }
  __syncthreads();

  // ---- layer 2: out(64x128) = hidden @ W1b + b1b; wave owns 32 cols ----
  const int n2 = wave * 32;
  float bias2[2];
#pragma unroll
  for (int nt = 0; nt < 2; ++nt) bias2[nt] = b1b[n2 + nt * 16 + lr];

  f32x4 acc2[4][2];
#pragma unroll
  for (int mt = 0; mt < 4; ++mt)
#pragma unroll
    for (int nt = 0; nt < 2; ++nt) acc2[mt][nt] = (f32x4){0.f, 0.f, 0.f, 0.f};

#pragma unroll
  for (int ks = 0; ks < 8; ++ks) {
    const int k0 = ks * 32 + lq * 8;
    bf16x8 af[4], bv[2];
#pragma unroll
    for (int mt = 0; mt < 4; ++mt)
      af[mt] = *(const bf16x8*)&As[mt * 16 + lr][k0];
#pragma unroll
    for (int nt = 0; nt < 2; ++nt)
      bv[nt] = *(const bf16x8*)&Wt1b[(n2 + nt * 16 + lr) * 256 + k0];
#pragma unroll
    for (int mt = 0; mt < 4; ++mt)
#pragma unroll
      for (int nt = 0; nt < 2; ++nt)
        acc2[mt][nt] = __builtin_amdgcn_mfma_f32_16x16x32_bf16(
            af[mt], bv[nt], acc2[mt][nt], 0, 0, 0);
  }

  // ---- scatter-add into sum[col[e]] ----
#pragma unroll
  for (int mt = 0; mt < 4; ++mt)
#pragma unroll
    for (int nt = 0; nt < 2; ++nt) {
      const int colF = n2 + nt * 16 + lr;
#pragma unroll
      for (int r = 0; r < 4; ++r) {
        const int row = mt * 16 + lq * 4 + r;
        atomicAdd(&sum[colS[row] * 128 + colF], acc2[mt][nt][r] + bias2[nt]);
      }
    }
}

// Node MLP: out = relu([x|agg|u[batch]] @ W2a + b2a) @ W2b + b2b
__global__ __launch_bounds__(256) void node_mlp(
    const float* __restrict__ x, const float* __restrict__ u,
    const int* __restrict__ batch,
    const bf16_t* __restrict__ Wt2a, const float* __restrict__ b2a,
    const bf16_t* __restrict__ Wt2b, const float* __restrict__ b2b,
    const float* __restrict__ sum, const float* __restrict__ cnt,
    float* __restrict__ out) {
  __shared__ __align__(16) bf16_t As[64][392];  // 64 x 384 staged, reused as hidden
  const int tid = threadIdx.x;
  const int lane = tid & 63;
  const int wave = tid >> 6;
  const int n0 = blockIdx.x * 64;

  // ---- stage z = [x | sum/cnt | u[batch]]: 64 rows x 384 cols ----
  for (int v = tid; v < 64 * 96; v += 256) {
    const int i = v / 96;
    const int seg = v - i * 96;
    const int c0 = seg * 4;
    const int n = n0 + i;
    float4 f = make_float4(0.f, 0.f, 0.f, 0.f);
    if (n < NN) {
      if (c0 < 128) {
        f = *(const float4*)(x + n * 128 + c0);
      } else if (c0 < 256) {
        const float inv = 1.0f / fmaxf(cnt[n], 1.0f);
        float4 s = *(const float4*)(sum + n * 128 + (c0 - 128));
        f = make_float4(s.x * inv, s.y * inv, s.z * inv, s.w * inv);
      } else {
        const int g = batch[n];
        f = *(const float4*)(u + g * 128 + (c0 - 256));
      }
    }
    union { bf16_t h[4]; uint2 uu; } pk;
    pk.h[0] = (bf16_t)f.x; pk.h[1] = (bf16_t)f.y;
    pk.h[2] = (bf16_t)f.z; pk.h[3] = (bf16_t)f.w;
    *(uint2*)&As[i][c0] = pk.uu;
  }
  __syncthreads();

  const int lr = lane & 15;
  const int lq = lane >> 4;

  // ---- layer 1: hidden(64x256) = relu(z @ W2a + b2a) ----
  const int n_off = wave * 64;
  float bias1[4];
#pragma unroll
  for (int nt = 0; nt < 4; ++nt) bias1[nt] = b2a[n_off + nt * 16 + lr];

  f32x4 acc[4][4];
#pragma unroll
  for (int mt = 0; mt < 4; ++mt)
#pragma unroll
    for (int nt = 0; nt < 4; ++nt) acc[mt][nt] = (f32x4){0.f, 0.f, 0.f, 0.f};

#pragma unroll
  for (int ks = 0; ks < 12; ++ks) {
    const int k0 = ks * 32 + lq * 8;
    bf16x8 af[4], bv[4];
#pragma unroll
    for (int mt = 0; mt < 4; ++mt)
      af[mt] = *(const bf16x8*)&As[mt * 16 + lr][k0];
#pragma unroll
    for (int nt = 0; nt < 4; ++nt)
      bv[nt] = *(const bf16x8*)&Wt2a[(n_off + nt * 16 + lr) * 384 + k0];
#pragma unroll
    for (int mt = 0; mt < 4; ++mt)
#pragma unroll
      for (int nt = 0; nt < 4; ++nt)
        acc[mt][nt] = __builtin_amdgcn_mfma_f32_16x16x32_bf16(
            af[mt], bv[nt], acc[mt][nt], 0, 0, 0);
  }
  __syncthreads();
#pragma unroll
  for (int mt = 0; mt < 4; ++mt)
#pragma unroll
    for (int nt = 0; nt < 4; ++nt) {
      const int row = mt * 16 + lq * 4;
      const int colF = n_off + nt * 16 + lr;
#pragma unroll
      for (int r = 0; r < 4; ++r) {
        float v = acc[mt][nt][r] + bias1[nt];
        As[row + r][colF] = (bf16_t)fmaxf(v, 0.f);
      }
    }
  __syncthreads();

  // ---- layer 2: out(64x128) = hidden @ W2b + b2b ----
  const int n2 = wave * 32;
  float bias2[2];
#pragma unroll
  for (int nt = 0; nt < 2; ++nt) bias2[nt] = b2b[n2 + nt * 16 + lr];

  f32x4 acc2[4][2];
#pragma unroll
  for (int mt = 0; mt < 4; ++mt)
#pragma unroll
    for (int nt = 0; nt < 2; ++nt) acc2[mt][nt] = (f32x4){0.f, 0.f, 0.f, 0.f};

#pragma unroll
  for (int ks = 0; ks < 8; ++ks) {
    const int k0 = ks * 32 + lq * 8;
    bf16x8 af[4], bv[2];
#pragma unroll
    for (int mt = 0; mt < 4; ++mt)
      af[mt] = *(const bf16x8*)&As[mt * 16 + lr][k0];
#pragma unroll
    for (int nt = 0; nt < 2; ++nt)
      bv[nt] = *(const bf16x8*)&Wt2b[(n2 + nt * 16 + lr) * 256 + k0];
#pragma unroll
    for (int mt = 0; mt < 4; ++mt)
#pragma unroll
      for (int nt = 0; nt < 2; ++nt)
        acc2[mt][nt] = __builtin_amdgcn_mfma_f32_16x16x32_bf16(
            af[mt], bv[nt], acc2[mt][nt], 0, 0, 0);
  }

#pragma unroll
  for (int mt = 0; mt < 4; ++mt)
#pragma unroll
    for (int nt = 0; nt < 2; ++nt) {
      const int colF = n2 + nt * 16 + lr;
#pragma unroll
      for (int r = 0; r < 4; ++r) {
        const int row = mt * 16 + lq * 4 + r;
        const int n = n0 + row;
        if (n < NN) out[n * 128 + colF] = acc2[mt][nt][r] + bias2[nt];
      }
    }
}

extern "C" void kernel_launch(void* const* d_in, const int* in_sizes, int n_in,
                              void* d_out, int out_size, void* d_ws, size_t ws_size,
                              hipStream_t stream) {
  const float* x    = (const float*)d_in[0];
  const int*   ei   = (const int*)d_in[1];
  const float* ea   = (const float*)d_in[2];
  const float* u    = (const float*)d_in[3];
  const int*   batch= (const int*)d_in[4];
  const float* W1a  = (const float*)d_in[5];
  const float* b1a  = (const float*)d_in[6];
  const float* W1b  = (const float*)d_in[7];
  const float* b1b  = (const float*)d_in[8];
  const float* W2a  = (const float*)d_in[9];
  const float* b2a  = (const float*)d_in[10];
  const float* W2b  = (const float*)d_in[11];
  const float* b2b  = (const float*)d_in[12];

  char* ws = (char*)d_ws;
  float* sum = (float*)(ws + SUM_OFF);
  float* cnt = (float*)(ws + CNT_OFF);
  bf16_t* w1a = (bf16_t*)(ws + W1A_OFF);
  bf16_t* w1b = (bf16_t*)(ws + W1B_OFF);
  bf16_t* w2a = (bf16_t*)(ws + W2A_OFF);
  bf16_t* w2b = (bf16_t*)(ws + W2B_OFF);

  hipMemsetAsync(ws + SUM_OFF, 0, SUM_B + CNT_B, stream);
  transpose_bf16<<<256, 256, 0, stream>>>(W1a, w1a, 256, 256);
  transpose_bf16<<<128, 256, 0, stream>>>(W1b, w1b, 256, 128);
  transpose_bf16<<<384, 256, 0, stream>>>(W2a, w2a, 384, 256);
  transpose_bf16<<<128, 256, 0, stream>>>(W2b, w2b, 256, 128);
  edge_mlp<<<NE / 64, 256, 0, stream>>>(x, ei, ea, w1a, b1a, w1b, b1b, sum, cnt);
  node_mlp<<<(NN + 63) / 64, 256, 0, stream>>>(x, u, batch, w2a, b2a, w2b, b2b,
                                               sum, cnt, (float*)d_out);
}